// Round 10
// baseline (76.240 us; speedup 1.0000x reference)
//
#include <hip/hip_runtime.h>
#include <cmath>

#ifndef M_PI
#define M_PI 3.14159265358979323846
#endif

static constexpr int CH     = 128;
static constexpr int NBATCH = 64;
static constexpr int HWSZ   = 3136;
static constexpr int HW4    = 784;
static constexpr int PARTS  = 16;
static constexpr int SLPP   = NBATCH / PARTS;   // 4
static constexpr int KTOP   = 10;
static constexpr float EPSV = 1e-5f;
static constexpr int LBUF   = 512;              // k_main per-block LDS buffer
static constexpr int CAPMAX = 8192;             // k_select LDS capacity (16*512)

#define CSA(a,b) { float lo_=fminf(a,b), hi_=fmaxf(a,b); a=lo_; b=hi_; }
#define CHAIN(d) if ((d) > t0) { t0=(d); CSA(t0,t1);CSA(t1,t2);CSA(t2,t3); \
  CSA(t3,t4);CSA(t4,t5);CSA(t5,t6);CSA(t6,t7);CSA(t7,t8);CSA(t8,t9); }

// ---------------------------------------------------------------------------
// k_main: fused stats + sweep.  grid = PARTS*CH = 2048 blocks, 256 threads.
// Phase A: per-block redundant 2-slice sample (L2-broadcast) -> mu_hat, tau.
//          Identical data+order for the 16 blocks of a channel => identical
//          per-channel (mu_hat, tau) bit-for-bit.
// Phase B: exact partial sum + wave-gated candidate collect (raw v with
//          |v - mu_hat| >= tau) into a fixed per-block segment. No global
//          atomics, no zero-init needed (bcnt always stored).
// ---------------------------------------------------------------------------
__global__ __launch_bounds__(256) void k_main(const float* __restrict__ x,
                                              float* __restrict__ sums,
                                              unsigned* __restrict__ bcnt,
                                              float* __restrict__ cand,
                                              int seg, float tauf) {
  __shared__ float buf[LBUF];
  __shared__ unsigned lcnt;
  __shared__ float sh[4];
  __shared__ float sbc[2];          // broadcast mu_hat, tau
  const int bid  = blockIdx.x;
  const int c    = bid & (CH - 1);
  const int part = bid >> 7;
  const int tid  = threadIdx.x;
  const int lane = tid & 63, wid = tid >> 6;
  const float4* x4 = reinterpret_cast<const float4*>(x);

  // ---- Phase A: sample slices n=0 and n=32 (contiguous, L2-hot) ----
  const size_t b0 = (size_t)c * HW4;
  const size_t b1 = (size_t)(32 * CH + c) * HW4;
  float s = 0.f;
  for (int i = tid; i < HW4; i += 256) {
    float4 a = x4[b0 + i], b = x4[b1 + i];
    s += ((a.x + a.y) + (a.z + a.w)) + ((b.x + b.y) + (b.z + b.w));
  }
  for (int off = 32; off; off >>= 1) s += __shfl_down(s, off);
  if (lane == 0) sh[wid] = s;
  __syncthreads();
  if (tid == 0) sbc[0] = ((sh[0] + sh[1]) + (sh[2] + sh[3])) * (1.f / (2.f * HWSZ));
  __syncthreads();
  const float muh = sbc[0];

  float m = 0.f;
  for (int i = tid; i < HW4; i += 256) {
    float4 a = x4[b0 + i], b = x4[b1 + i];
    m = fmaxf(m, fmaxf(fmaxf(fabsf(a.x - muh), fabsf(a.y - muh)),
                       fmaxf(fabsf(a.z - muh), fabsf(a.w - muh))));
    m = fmaxf(m, fmaxf(fmaxf(fabsf(b.x - muh), fabsf(b.y - muh)),
                       fmaxf(fabsf(b.z - muh), fabsf(b.w - muh))));
  }
  for (int off = 32; off; off >>= 1) m = fmaxf(m, __shfl_down(m, off));
  if (lane == 0) sh[wid] = m;
  __syncthreads();
  if (tid == 0) {
    sbc[1] = tauf * fmaxf(fmaxf(sh[0], sh[1]), fmaxf(sh[2], sh[3]));
    lcnt = 0u;
  }
  __syncthreads();
  const float t = sbc[1];

  // ---- Phase B: sweep this block's 4 slices ----
  float s2 = 0.f;
  for (int sl = 0; sl < SLPP; ++sl) {
    const size_t base = (size_t)((part * SLPP + sl) * CH + c) * HW4;
    for (int i = tid; i < HW4; i += 256) {
      float4 v = x4[base + i];
      s2 += (v.x + v.y) + (v.z + v.w);
      float d0 = fabsf(v.x - muh), d1 = fabsf(v.y - muh);
      float d2 = fabsf(v.z - muh), d3 = fabsf(v.w - muh);
      float dm = fmaxf(fmaxf(d0, d1), fmaxf(d2, d3));
      if (__any(dm >= t)) {
        if (d0 >= t) { unsigned p = atomicAdd(&lcnt, 1u); if (p < LBUF) buf[p] = v.x; }
        if (d1 >= t) { unsigned p = atomicAdd(&lcnt, 1u); if (p < LBUF) buf[p] = v.y; }
        if (d2 >= t) { unsigned p = atomicAdd(&lcnt, 1u); if (p < LBUF) buf[p] = v.z; }
        if (d3 >= t) { unsigned p = atomicAdd(&lcnt, 1u); if (p < LBUF) buf[p] = v.w; }
      }
    }
  }
  for (int off = 32; off; off >>= 1) s2 += __shfl_down(s2, off);
  if (lane == 0) sh[wid] = s2;
  __syncthreads();   // all pushes + partials visible

  if (tid == 0) {
    sums[part * CH + c] = (sh[0] + sh[1]) + (sh[2] + sh[3]);
    bcnt[part * CH + c] = lcnt;          // true attempted count (may exceed seg)
  }
  const unsigned nw0 = lcnt;
  const unsigned nw  = nw0 < (unsigned)seg ? nw0 : (unsigned)seg;
  float* cc = cand + ((size_t)c * PARTS + part) * seg;
  for (unsigned i = tid; i < nw; i += 256) cc[i] = buf[i];
}

// ---------------------------------------------------------------------------
// k_select: per channel: exact mu; gather 16 segments; top-10 of |v-mu|;
// rescue fallback; fold (sw, sb).  grid = CH, 256 threads.
// ---------------------------------------------------------------------------
__global__ __launch_bounds__(256) void k_select(const float* __restrict__ x,
                                                const float* __restrict__ sums,
                                                const unsigned* __restrict__ bcnt,
                                                const float* __restrict__ cand,
                                                const float* __restrict__ weight,
                                                const float* __restrict__ bias,
                                                float* __restrict__ swg,
                                                float* __restrict__ sbg,
                                                int seg, float constv) {
  __shared__ float ls[CAPMAX];      // 32 KB (128-block kernel; occupancy moot)
  __shared__ float rwv[4];
  __shared__ int   rwi[4];
  const int c   = blockIdx.x;
  const int tid = threadIdx.x;
  const int lane = tid & 63, wid = tid >> 6;
  const float4* x4 = reinterpret_cast<const float4*>(x);

  float acc = 0.f;
  #pragma unroll
  for (int p = 0; p < PARTS; ++p) acc += sums[p * CH + c];
  const float mu = acc * (1.0f / ((float)NBATCH * (float)HWSZ));

  // per-part counts (redundant per thread; tiny)
  int cnts[PARTS];
  int total = 0;
  bool good = true;
  #pragma unroll
  for (int p = 0; p < PARTS; ++p) {
    cnts[p] = (int)bcnt[p * CH + c];
    if (cnts[p] > seg) good = false;
    total += cnts[p];
  }
  if (total < KTOP) good = false;

  int m;
  if (good) {
    int off = 0;
    for (int p = 0; p < PARTS; ++p) {
      const int n = cnts[p];
      const float* sp = cand + ((size_t)c * PARTS + p) * seg;
      for (int i = tid; i < n; i += 256) ls[off + i] = fabsf(sp[i] - mu);
      off += n;
    }
    m = off;
  } else {
    // rescue: full-channel per-thread top-10 chain (exact; fires only when
    // the threshold certification fails)
    float t0=-1.f,t1=-1.f,t2=-1.f,t3=-1.f,t4=-1.f,
          t5=-1.f,t6=-1.f,t7=-1.f,t8=-1.f,t9=-1.f;
    for (int sl = 0; sl < NBATCH; ++sl) {
      const size_t base = (size_t)(sl * CH + c) * HW4;
      for (int i = tid; i < HW4; i += 256) {
        float4 v = x4[base + i];
        float d0 = fabsf(v.x - mu), d1 = fabsf(v.y - mu);
        float d2 = fabsf(v.z - mu), d3 = fabsf(v.w - mu);
        CHAIN(d0); CHAIN(d1); CHAIN(d2); CHAIN(d3);
      }
    }
    ls[0*256+tid]=t0; ls[1*256+tid]=t1; ls[2*256+tid]=t2; ls[3*256+tid]=t3;
    ls[4*256+tid]=t4; ls[5*256+tid]=t5; ls[6*256+tid]=t6; ls[7*256+tid]=t7;
    ls[8*256+tid]=t8; ls[9*256+tid]=t9;
    m = KTOP * 256;
  }
  __syncthreads();

  float tot = 0.f;
  for (int it = 0; it < KTOP; ++it) {
    float best = -1.f; int bi = 0;
    for (int i = tid; i < m; i += 256) {
      float v = ls[i];
      if (v > best) { best = v; bi = i; }
    }
    for (int off = 32; off; off >>= 1) {
      float ov = __shfl_down(best, off);
      int   oi = __shfl_down(bi, off);
      if (ov > best) { best = ov; bi = oi; }
    }
    if (lane == 0) { rwv[wid] = best; rwi[wid] = bi; }
    __syncthreads();
    if (tid == 0) {
      float bb = rwv[0]; int bbi = rwi[0];
      for (int w = 1; w < 4; ++w) if (rwv[w] > bb) { bb = rwv[w]; bbi = rwi[w]; }
      tot += bb;
      ls[bbi] = -1.f;
    }
    __syncthreads();
  }

  if (tid == 0) {
    const float mtk = tot * (1.0f / KTOP) * constv;
    const float inv = 1.f / (mtk + EPSV);
    const float w   = inv * weight[c];
    swg[c] = w;
    sbg[c] = bias[c] - mu * w;
  }
}

// ---------------------------------------------------------------------------
// k_affine: pure stream, zero LDS.  grid = PARTS*CH, 256 threads.
// ---------------------------------------------------------------------------
__global__ __launch_bounds__(256) void k_affine(const float* __restrict__ x,
                                                const float* __restrict__ swg,
                                                const float* __restrict__ sbg,
                                                float* __restrict__ out) {
  const int bid  = blockIdx.x;
  const int c    = bid & (CH - 1);
  const int part = bid >> 7;
  const float w = swg[c], b = sbg[c];
  const float4* x4 = reinterpret_cast<const float4*>(x);
  float4* o4 = reinterpret_cast<float4*>(out);
  #pragma unroll
  for (int sl = 0; sl < SLPP; ++sl) {
    const size_t base = (size_t)((part * SLPP + sl) * CH + c) * HW4;
    for (int i = threadIdx.x; i < HW4; i += 256) {
      float4 v = x4[base + i];
      float4 r;
      r.x = fmaf(v.x, w, b);
      r.y = fmaf(v.y, w, b);
      r.z = fmaf(v.z, w, b);
      r.w = fmaf(v.w, w, b);
      o4[base + i] = r;
    }
  }
}

extern "C" void kernel_launch(void* const* d_in, const int* in_sizes, int n_in,
                              void* d_out, int out_size, void* d_ws, size_t ws_size,
                              hipStream_t stream) {
  const float* x      = (const float*)d_in[0];
  const float* weight = (const float*)d_in[1];
  const float* bias   = (const float*)d_in[2];
  float* out = (float*)d_out;
  float* ws  = (float*)d_ws;

  // ws layout (floats); nothing needs zero-init (bcnt/sums always stored)
  float*    sums = ws;                          // PARTS*CH = 2048
  float*    swg  = sums + PARTS * CH;           // 128
  float*    sbg  = swg + CH;                    // 128
  unsigned* bcnt = (unsigned*)(sbg + CH);       // PARTS*CH = 2048
  float*    cand = (float*)(bcnt + PARTS * CH); // CH*PARTS*seg
  const size_t FIXED = (size_t)((float*)cand - ws);

  const size_t avail = ws_size / 4;
  int seg; float tauf;
  if      (avail >= FIXED + (size_t)CH * PARTS * 512) { seg = 512; tauf = 0.72f; }
  else if (avail >= FIXED + (size_t)CH * PARTS * 256) { seg = 256; tauf = 0.82f; }
  else                                                { seg = 128; tauf = 0.90f; }

  const double M = (double)NBATCH * (double)HWSZ;
  const float constv =
      (float)(0.5 * (1.0 + sqrt(M_PI * log(4.0))) / sqrt(2.0 * log(M)));

  k_main<<<PARTS * CH, 256, 0, stream>>>(x, sums, bcnt, cand, seg, tauf);
  k_select<<<CH, 256, 0, stream>>>(x, sums, bcnt, cand, weight, bias,
                                   swg, sbg, seg, constv);
  k_affine<<<PARTS * CH, 256, 0, stream>>>(x, swg, sbg, out);
}